// Round 5
// baseline (566.724 us; speedup 1.0000x reference)
//
#include <hip/hip_runtime.h>
#include <hip/hip_bf16.h>
#include <math.h>

#define NTOK   8192
#define HIDDEN 2048
#define FFN_   2048
#define NEXP   8
#define TOPK   2
#define MTOT   (NTOK*TOPK)   // 16384 scattered rows
#define CAP    (MTOT/NEXP)   // 2048 rows per expert
#define KD     2048          // K of both GEMMs
#define NT     32            // K-tiles of 64

typedef __bf16 bf16_t;
typedef __attribute__((ext_vector_type(8))) __bf16 bf16x8;
typedef __attribute__((ext_vector_type(4))) float  f32x4;

__device__ __forceinline__ void async16(const bf16_t* g, bf16_t* l) {
    __builtin_amdgcn_global_load_lds(
        (const __attribute__((address_space(1))) void*)g,
        (__attribute__((address_space(3))) void*)l, 16, 0, 0);
}

#define FENCE() asm volatile("" ::: "memory")
#define BAR()   do { FENCE(); __builtin_amdgcn_s_barrier(); FENCE(); } while (0)

// inv build + pairing probe + x fp32->bf16 cast, one dispatch (2048 blocks)
__global__ __launch_bounds__(256)
void k_prep(const int* __restrict__ scat, int* __restrict__ inv,
            int* __restrict__ flag, const float* __restrict__ x,
            bf16_t* __restrict__ xb) {
    int b = blockIdx.x, t = threadIdx.x;
    if (b < MTOT / 256) {
        int i = b * 256 + t;
        inv[scat[i]] = i;
        if (i < NTOK && ((scat[2 * i] ^ scat[2 * i + 1]) != 1)) atomicOr(flag, 1);
    }
    const size_t QX = (size_t)NTOK * HIDDEN / 4;
    size_t t0 = (size_t)b * 256 + t, stride = (size_t)gridDim.x * 256;
    for (size_t i = t0; i < QX; i += stride) {
        float4 v = ((const float4*)x)[i];
        __attribute__((ext_vector_type(4))) __bf16 o;
        o[0] = (bf16_t)v.x; o[1] = (bf16_t)v.y; o[2] = (bf16_t)v.z; o[3] = (bf16_t)v.w;
        ((__attribute__((ext_vector_type(4))) __bf16*)xb)[i] = o;
    }
}

// zero the fp32 output ONLY in unpaired-fallback mode (atomics need it);
// paired mode plain-stores every element exactly once.
__global__ __launch_bounds__(256)
void k_zero(float* __restrict__ out, const int* __restrict__ flag) {
    if (*flag == 0) return;
    const size_t QO = (size_t)NTOK * HIDDEN / 4;
    size_t t0 = (size_t)blockIdx.x * 256 + threadIdx.x;
    size_t stride = (size_t)gridDim.x * 256;
    float4 z = {0.f, 0.f, 0.f, 0.f};
    for (size_t i = t0; i < QO; i += stride) ((float4*)out)[i] = z;
}

// ---------------------------------------------------------------------------
// 256x256-tile grouped GEMM, C = A*B^T per expert, K=2048, BK=64, 8 waves.
// A: bf16, staged via global_load_lds (source-swizzled, linear dest).
// B: *** fp32 *** , reg-staged (T14): 2 batches x 4 float4/thread/K-tile,
//    cvt->bf16, ds_write_b128 into the SAME swizzled layout the readers use.
//    Legal because bfn/bf1 scheme finishes all B-LDS-reads of a buffer by q1.
// Phases: q0: dsA(0)+BLDH(j+2,0)+STGA(h1,j+1) -> M(0,0)xbfn
//         q1: dsB1                            -> M(0,1)xbf1
//         q2: dsA(1)+BWRH(0)+BLDH(j+2,1)      -> M(1,0)xbfn
//         q3: BWRH(1)+STGA(h0,j+2)+vmcnt(2)+lgkm(0); LOADB0N(next) -> M(1,1)
// paired mode (flag==0): 1024 unique rows/expert, EPI1 plain-stores 2*acc.
// ---------------------------------------------------------------------------
template <int EPI>
__global__ __launch_bounds__(512, 2)
void k_gemm(const bf16_t* __restrict__ A, const float* __restrict__ B,
            bf16_t* __restrict__ Hout, float* __restrict__ Out,
            const int* __restrict__ inv, const int* __restrict__ flag)
{
    const int paired = (*flag == 0);
    const int per_e  = paired ? 32 : 64;
    int idx = blockIdx.x >> 3;
    int e   = blockIdx.x & 7;                    // T1: expert == XCD
    if (idx >= per_e) return;
    int row0 = (idx >> 3) * 256;
    int col0 = (idx & 7) * 256;
    const int Mcap = paired ? 1024 : 2048;
    const float* Bf = B + (size_t)e * 2048 * KD;

    __shared__ __align__(16) bf16_t lds[2 * 2 * 16384];   // 128 KiB

    int tid  = threadIdx.x;
    int lane = tid & 63;
    int wid  = tid >> 6;
    int wm   = wid >> 2;                // 0..1: A-half
    int wn   = wid & 3;                 // 0..3: B-quarter

    // ---- A staging source pointers (global slot pre-swizzled) ----
    int rr = tid >> 3;
    int g8 = ((tid & 7) ^ (rr & 7)) * 8;
    const bf16_t* ap[2][2];
    #pragma unroll
    for (int h = 0; h < 2; h++)
        #pragma unroll
        for (int l = 0; l < 2; l++) {
            int ra = row0 + h * 128 + l * 64 + rr;
            if (EPI == 0) {
                int sidx = paired ? 2 * (e * 1024 + ra) : (e * 2048 + ra);
                ap[h][l] = A + (size_t)(inv[sidx] / TOPK) * KD + g8;
            } else {
                ap[h][l] = A + ((size_t)e * Mcap + ra) * KD + g8;
            }
        }

    // ---- B fp32 reg-staging: thread covers row rr2, k-half kh (32 floats) ----
    int rr2 = tid >> 1;
    int kh  = (tid & 1) * 32;
    const float* bqf = Bf + ((size_t)(col0 + rr2)) * KD + kh;
    float4 bld[4];

#define STGA(h_, jt) do { \
        bf16_t* d_ = lds + (((jt) & 1) * 32768 + (h_) * 8192 + tid * 8); \
        async16(ap[h_][0] + (size_t)(jt) * 64, d_); \
        async16(ap[h_][1] + (size_t)(jt) * 64, d_ + 4096); \
    } while (0)

#define BLDH(jt, half) do { _Pragma("unroll") \
        for (int q = 0; q < 4; q++) \
            bld[q] = ((const float4*)(bqf + (size_t)(jt) * 64))[(half) * 4 + q]; \
    } while (0)

#define BWRH(jt, half) do { \
        char* bb_ = (char*)(lds + ((jt) & 1) * 32768 + 16384); \
        _Pragma("unroll") \
        for (int q = 0; q < 2; q++) { \
            float4 u_ = bld[2 * q], v_ = bld[2 * q + 1]; \
            bf16x8 o_; \
            o_[0]=(bf16_t)u_.x; o_[1]=(bf16_t)u_.y; o_[2]=(bf16_t)u_.z; o_[3]=(bf16_t)u_.w; \
            o_[4]=(bf16_t)v_.x; o_[5]=(bf16_t)v_.y; o_[6]=(bf16_t)v_.z; o_[7]=(bf16_t)v_.w; \
            int kk_ = kh + (half) * 16 + q * 8; \
            *(bf16x8*)(bb_ + ((rr2 * 128 + kk_ * 2) ^ ((rr2 & 7) << 4))) = o_; \
        } } while (0)

    // ---- compute-side fragment addressing (T2 swizzled read) ----
    int lm  = lane & 15;
    int lkq = lane >> 4;
    int sw  = (lane & 7) << 4;
    int cA0 = ((lkq * 16) ^ sw) >> 1;
    int cA1 = ((64 + lkq * 16) ^ sw) >> 1;

    f32x4  acc[8][4] = {};
    bf16x8 af[4][2];          // A quadrant (reloaded q0/q2)
    bf16x8 bfn[2][2];         // B quadrant 0 (prefetched at q3 from next buffer)
    bf16x8 bf1[2][2];         // B quadrant 1 (loaded in-phase at q1)

#define LOADA(qm) do { _Pragma("unroll") \
        for (int i = 0; i < 4; i++) { \
            const bf16_t* rp_ = Ab + (wm * 128 + (qm) * 64 + i * 16 + lm) * 64; \
            af[i][0] = *(const bf16x8*)(rp_ + cA0); \
            af[i][1] = *(const bf16x8*)(rp_ + cA1); } } while (0)

#define LOADB1() do { _Pragma("unroll") \
        for (int jj = 0; jj < 2; jj++) { \
            const bf16_t* rp_ = Bb + (wn * 64 + 32 + jj * 16 + lm) * 64; \
            bf1[jj][0] = *(const bf16x8*)(rp_ + cA0); \
            bf1[jj][1] = *(const bf16x8*)(rp_ + cA1); } } while (0)

#define LOADB0N(Bsrc) do { _Pragma("unroll") \
        for (int jj = 0; jj < 2; jj++) { \
            const bf16_t* rp_ = (Bsrc) + (wn * 64 + jj * 16 + lm) * 64; \
            bfn[jj][0] = *(const bf16x8*)(rp_ + cA0); \
            bfn[jj][1] = *(const bf16x8*)(rp_ + cA1); } } while (0)

#define MFMAQ(qm, BARR) do { \
        __builtin_amdgcn_s_setprio(1); \
        _Pragma("unroll") \
        for (int i = 0; i < 4; i++) \
            _Pragma("unroll") \
            for (int jj = 0; jj < 2; jj++) { \
                acc[(qm)*4+i][(BQ)*2+jj] = __builtin_amdgcn_mfma_f32_16x16x32_bf16( \
                    af[i][0], BARR[jj][0], acc[(qm)*4+i][(BQ)*2+jj], 0, 0, 0); \
                acc[(qm)*4+i][(BQ)*2+jj] = __builtin_amdgcn_mfma_f32_16x16x32_bf16( \
                    af[i][1], BARR[jj][1], acc[(qm)*4+i][(BQ)*2+jj], 0, 0, 0); \
            } \
        __builtin_amdgcn_s_setprio(0); \
    } while (0)

    // ---- prologue: A tiles 0,1(h0) via async16; B tiles 0,1 via reg-staging
    STGA(0, 0); STGA(1, 0); STGA(0, 1);                 // 6 async16
    BLDH(0, 0); BWRH(0, 0); BLDH(0, 1); BWRH(0, 1);     // B tile0
    BLDH(1, 0); BWRH(1, 0); BLDH(1, 1); BWRH(1, 1);     // B tile1
    asm volatile("s_waitcnt vmcnt(2) lgkmcnt(0)" ::: "memory");  // A(0) resident, B writes done
    BAR();
    {   // prefetch B0 quadrant of tile 0
        const bf16_t* Bb0 = lds + 16384;
        LOADB0N(Bb0);
    }

    for (int j = 0; j < NT; ++j) {
        const bf16_t* Ab = lds + (j & 1) * 32768;
        const bf16_t* Bb = Ab + 16384;
        // ---- q0: M(0,0) = A0 x B0(bfn)
        LOADA(0);
        if (j + 2 < NT) BLDH(j + 2, 0);
        if (j + 1 < NT) STGA(1, j + 1);
        BAR();
        { enum { BQ = 0 }; MFMAQ(0, bfn); }
        BAR();
        // ---- q1: M(0,1) = A0 x B1   (last B-LDS-read of current buffer)
        LOADB1();
        BAR();
        { enum { BQ = 1 }; MFMAQ(0, bf1); }
        BAR();
        // ---- q2: M(1,0) = A1 x B0(bfn); B region of current buf now writable
        LOADA(1);
        if (j + 2 < NT) { BWRH(j + 2, 0); BLDH(j + 2, 1); }
        BAR();
        { enum { BQ = 0 }; MFMAQ(1, bfn); }
        BAR();
        // ---- q3: M(1,1) = A1 x B1; finish B(j+2) writes; certify tile j+1
        if (j + 2 < NT) {
            BWRH(j + 2, 1);
            STGA(0, j + 2);
            asm volatile("s_waitcnt vmcnt(2) lgkmcnt(0)" ::: "memory");
        } else if (j + 1 < NT) {
            asm volatile("s_waitcnt vmcnt(0)" ::: "memory");
        }
        BAR();
        if (j + 1 < NT) {
            const bf16_t* Bbn = lds + (((j + 1) & 1) * 32768) + 16384;
            LOADB0N(Bbn);
        }
        { enum { BQ = 1 }; MFMAQ(1, bf1); }
        BAR();
    }

    // ---- epilogue: frag (row,col): row = lkq*4 + reg (+frag base), col = lane&15
    int rbase = lkq * 4;
    if (EPI == 0) {
        #pragma unroll
        for (int mi = 0; mi < 8; mi++) {
            int row = row0 + wm * 128 + mi * 16 + rbase;
            #pragma unroll
            for (int nj = 0; nj < 4; nj++) {
                int col = col0 + wn * 64 + nj * 16 + lm;
                #pragma unroll
                for (int r = 0; r < 4; r++) {
                    float v = acc[mi][nj][r];
                    v = 0.5f * v * (1.0f + erff(v * 0.70710678118f));
                    Hout[((size_t)e * Mcap + row + r) * FFN_ + col] = (bf16_t)v;
                }
            }
        }
    } else if (paired) {
        #pragma unroll
        for (int mi = 0; mi < 8; mi++) {
            #pragma unroll
            for (int r = 0; r < 4; r++) {
                int u   = e * 1024 + row0 + wm * 128 + mi * 16 + rbase + r;
                int tok = inv[2 * u] / TOPK;
                #pragma unroll
                for (int nj = 0; nj < 4; nj++) {
                    int col = col0 + wn * 64 + nj * 16 + lm;
                    Out[(size_t)tok * HIDDEN + col] = 2.0f * acc[mi][nj][r];
                }
            }
        }
    } else {
        #pragma unroll
        for (int mi = 0; mi < 8; mi++) {
            #pragma unroll
            for (int r = 0; r < 4; r++) {
                int gm  = e * 2048 + row0 + wm * 128 + mi * 16 + rbase + r;
                int tok = inv[gm] / TOPK;
                #pragma unroll
                for (int nj = 0; nj < 4; nj++) {
                    int col = col0 + wn * 64 + nj * 16 + lm;
                    atomicAdd(&Out[(size_t)tok * HIDDEN + col], acc[mi][nj][r]);
                }
            }
        }
    }
#undef STGA
#undef BLDH
#undef BWRH
#undef LOADA
#undef LOADB1
#undef LOADB0N
#undef MFMAQ
}

extern "C" void kernel_launch(void* const* d_in, const int* in_sizes, int n_in,
                              void* d_out, int out_size, void* d_ws, size_t ws_size,
                              hipStream_t stream) {
    const float* x    = (const float*)d_in[0];
    const float* w1   = (const float*)d_in[1];
    const float* w2   = (const float*)d_in[2];
    const int*   scat = (const int*)d_in[3];
    float* out = (float*)d_out;

    char* ws = (char*)d_ws;
    size_t off = 0;
    int*    inv   = (int*)(ws + off);   off += 65536;                          // MTOT*4
    int*    flagp = (int*)(ws + off);   off += 256;
    bf16_t* xbt = (bf16_t*)(ws + off);  off += (size_t)NTOK * HIDDEN * 2;      // 32 MB
    bf16_t* hb  = (bf16_t*)(ws + off);  off += (size_t)MTOT * FFN_ * 2;        // 64 MB

    hipMemsetAsync(flagp, 0, 4, stream);

    k_prep<<<2048, 256, 0, stream>>>(scat, inv, flagp, x, xbt);
    k_zero<<<2048, 256, 0, stream>>>(out, flagp);

    k_gemm<0><<<NEXP * 64, 512, 0, stream>>>(xbt, w1, hb, nullptr, inv, flagp);
    k_gemm<1><<<NEXP * 64, 512, 0, stream>>>(hb, w2, nullptr, out, inv, flagp);
}

// Round 6
// 481.006 us; speedup vs baseline: 1.1782x; 1.1782x over previous
//
#include <hip/hip_runtime.h>
#include <hip/hip_bf16.h>
#include <math.h>

#define NTOK   8192
#define HIDDEN 2048
#define FFN_   2048
#define NEXP   8
#define TOPK   2
#define MTOT   (NTOK*TOPK)   // 16384 scattered rows
#define CAP    (MTOT/NEXP)   // 2048 rows per expert
#define KD     2048          // K of both GEMMs
#define NT     32            // K-tiles of 64

typedef __bf16 bf16_t;
typedef __attribute__((ext_vector_type(8))) __bf16 bf16x8;
typedef __attribute__((ext_vector_type(4))) __bf16 bf16x4;
typedef __attribute__((ext_vector_type(4))) float  f32x4;

__device__ __forceinline__ void async16(const bf16_t* g, bf16_t* l) {
    __builtin_amdgcn_global_load_lds(
        (const __attribute__((address_space(1))) void*)g,
        (__attribute__((address_space(3))) void*)l, 16, 0, 0);
}

#define FENCE() asm volatile("" ::: "memory")
#define BAR()   do { FENCE(); __builtin_amdgcn_s_barrier(); FENCE(); } while (0)

// inv build + pairing probe + x fp32->bf16 cast, one dispatch (2048 blocks)
__global__ __launch_bounds__(256)
void k_prep(const int* __restrict__ scat, int* __restrict__ inv,
            int* __restrict__ flag, const float* __restrict__ x,
            bf16_t* __restrict__ xb) {
    int b = blockIdx.x, t = threadIdx.x;
    if (b < MTOT / 256) {
        int i = b * 256 + t;
        inv[scat[i]] = i;
        if (i < NTOK && ((scat[2 * i] ^ scat[2 * i + 1]) != 1)) atomicOr(flag, 1);
    }
    const size_t QX = (size_t)NTOK * HIDDEN / 4;
    size_t t0 = (size_t)b * 256 + t, stride = (size_t)gridDim.x * 256;
    for (size_t i = t0; i < QX; i += stride) {
        float4 v = ((const float4*)x)[i];
        bf16x4 o;
        o[0] = (bf16_t)v.x; o[1] = (bf16_t)v.y; o[2] = (bf16_t)v.z; o[3] = (bf16_t)v.w;
        ((bf16x4*)xb)[i] = o;
    }
}

// w1 fp32 -> bf16 (w2 is consumed fp32 by GEMM2 directly)
__global__ __launch_bounds__(256)
void k_wcast(const float* __restrict__ w1, bf16_t* __restrict__ w1b) {
    const size_t QW = (size_t)NEXP * FFN_ * HIDDEN / 4;
    size_t t0 = (size_t)blockIdx.x * 256 + threadIdx.x;
    size_t stride = (size_t)gridDim.x * 256;
    for (size_t i = t0; i < QW; i += stride) {
        float4 v = ((const float4*)w1)[i];
        bf16x4 o;
        o[0] = (bf16_t)v.x; o[1] = (bf16_t)v.y; o[2] = (bf16_t)v.z; o[3] = (bf16_t)v.w;
        ((bf16x4*)w1b)[i] = o;
    }
}

// zero fp32 output ONLY in unpaired-fallback mode (atomics need it)
__global__ __launch_bounds__(256)
void k_zero(float* __restrict__ out, const int* __restrict__ flag) {
    if (*flag == 0) return;
    const size_t QO = (size_t)NTOK * HIDDEN / 4;
    size_t t0 = (size_t)blockIdx.x * 256 + threadIdx.x;
    size_t stride = (size_t)gridDim.x * 256;
    float4 z = {0.f, 0.f, 0.f, 0.f};
    for (size_t i = t0; i < QO; i += stride) ((float4*)out)[i] = z;
}

// ---------------------------------------------------------------------------
// 256x256-tile grouped GEMM, C = A*B^T per expert, K=2048, BK=64, 8 waves.
// EPI=0 (GEMM1): A = xbt gathered via inv (bf16), B = w1b bf16 via async16.
//   Proven round-3 structure verbatim: vmcnt(6), B staged q2.
// EPI=1 (GEMM2): A = hb bf16 via async16, B = *** w2 fp32 reg-staged ***:
//   thread map r=tid>>4, seg=tid&15 -> each global_load_dwordx4 is 4x256B
//   fully-used segments (fix of round-5's 64-line scatter). BLD(h0)@q0 ->
//   BWR@q2 (2 phases), BLD(h1)@q2 -> BWR@q3 (1 phase, mostly L2). 8B
//   ds_writes into the same XOR-swizzled layout readers use. vmcnt(2).
// paired mode (flag==0): 1024 unique rows/expert, EPI1 plain-stores 2*acc.
// ---------------------------------------------------------------------------
template <int EPI>
__global__ __launch_bounds__(512, 2)
void k_gemm(const bf16_t* __restrict__ A, const bf16_t* __restrict__ Bb16,
            const float* __restrict__ Bf32,
            bf16_t* __restrict__ Hout, float* __restrict__ Out,
            const int* __restrict__ inv, const int* __restrict__ flag)
{
    const int paired = (*flag == 0);
    const int per_e  = paired ? 32 : 64;
    int idx = blockIdx.x >> 3;
    int e   = blockIdx.x & 7;                    // T1: expert == XCD
    if (idx >= per_e) return;
    int row0 = (idx >> 3) * 256;
    int col0 = (idx & 7) * 256;
    const int Mcap = paired ? 1024 : 2048;

    __shared__ __align__(16) bf16_t lds[2 * 2 * 16384];   // 128 KiB

    int tid  = threadIdx.x;
    int lane = tid & 63;
    int wid  = tid >> 6;
    int wm   = wid >> 2;                // 0..1: A-half
    int wn   = wid & 3;                 // 0..3: B-quarter

    // ---- A staging source pointers (global slot pre-swizzled) ----
    int rr = tid >> 3;
    int g8 = ((tid & 7) ^ (rr & 7)) * 8;
    const bf16_t* ap[2][2];
    const bf16_t* bp[2][2];
    const bf16_t* apb = A + ((size_t)e * Mcap + row0 + rr) * KD + g8;  // EPI1
    #pragma unroll
    for (int h = 0; h < 2; h++)
        #pragma unroll
        for (int l = 0; l < 2; l++) {
            if (EPI == 0) {
                int ra = row0 + h * 128 + l * 64 + rr;
                int sidx = paired ? 2 * (e * 1024 + ra) : (e * 2048 + ra);
                ap[h][l] = A + (size_t)(inv[sidx] / TOPK) * KD + g8;
                bp[h][l] = Bb16 + ((size_t)e * 2048 + col0 + h * 128 + l * 64 + rr) * KD + g8;
            }
        }

    // ---- B fp32 reg-staging (EPI1): r=tid>>4 row-in-32-group, seg=tid&15 ----
    const float* bqf = Bf32 + ((size_t)e * 2048 + col0 + (tid >> 4)) * KD + (tid & 15) * 4;
    f32x4 bld[4];

#define APTR(h_, l_) (EPI == 0 ? ap[h_][l_] : apb + (size_t)((h_) * 128 + (l_) * 64) * KD)

#define STGA(h_, jt) do { \
        bf16_t* d_ = lds + (((jt) & 1) * 32768 + (h_) * 8192 + tid * 8); \
        async16(APTR(h_, 0) + (size_t)(jt) * 64, d_); \
        async16(APTR(h_, 1) + (size_t)(jt) * 64, d_ + 4096); \
    } while (0)

#define STGB(h_, jt) do { \
        bf16_t* d_ = lds + (((jt) & 1) * 32768 + 16384 + (h_) * 8192 + tid * 8); \
        async16(bp[h_][0] + (size_t)(jt) * 64, d_); \
        async16(bp[h_][1] + (size_t)(jt) * 64, d_ + 4096); \
    } while (0)

#define BLD(jt, half) do { _Pragma("unroll") \
        for (int q = 0; q < 4; q++) \
            bld[q] = *(const f32x4*)(bqf + (size_t)((half) * 128 + q * 32) * KD + (size_t)(jt) * 64); \
    } while (0)

#define BWR(jt, half) do { \
        char* bb_ = (char*)(lds + (((jt) & 1) * 32768 + 16384)); \
        _Pragma("unroll") \
        for (int q = 0; q < 4; q++) { \
            f32x4 v_ = bld[q]; \
            bf16x4 o_; \
            o_[0] = (bf16_t)v_[0]; o_[1] = (bf16_t)v_[1]; \
            o_[2] = (bf16_t)v_[2]; o_[3] = (bf16_t)v_[3]; \
            int row_ = (half) * 128 + q * 32 + (tid >> 4); \
            *(bf16x4*)(bb_ + ((row_ * 128 + (tid & 15) * 8) ^ ((row_ & 7) << 4))) = o_; \
        } } while (0)

    // ---- compute-side fragment addressing (T2 swizzled read) ----
    int lm  = lane & 15;
    int lkq = lane >> 4;
    int sw  = (lane & 7) << 4;
    int cA0 = ((lkq * 16) ^ sw) >> 1;
    int cA1 = ((64 + lkq * 16) ^ sw) >> 1;

    f32x4  acc[8][4] = {};
    bf16x8 af[4][2];          // A quadrant (reloaded q0/q2)
    bf16x8 bfn[2][2];         // B quadrant 0 (prefetched at q3 from next buffer)
    bf16x8 bf1[2][2];         // B quadrant 1 (loaded in-phase at q1)

#define LOADA(qm) do { _Pragma("unroll") \
        for (int i = 0; i < 4; i++) { \
            const bf16_t* rp_ = Ab + (wm * 128 + (qm) * 64 + i * 16 + lm) * 64; \
            af[i][0] = *(const bf16x8*)(rp_ + cA0); \
            af[i][1] = *(const bf16x8*)(rp_ + cA1); } } while (0)

#define LOADB1() do { _Pragma("unroll") \
        for (int jj = 0; jj < 2; jj++) { \
            const bf16_t* rp_ = Bb + (wn * 64 + 32 + jj * 16 + lm) * 64; \
            bf1[jj][0] = *(const bf16x8*)(rp_ + cA0); \
            bf1[jj][1] = *(const bf16x8*)(rp_ + cA1); } } while (0)

#define LOADB0N(Bsrc) do { _Pragma("unroll") \
        for (int jj = 0; jj < 2; jj++) { \
            const bf16_t* rp_ = (Bsrc) + (wn * 64 + jj * 16 + lm) * 64; \
            bfn[jj][0] = *(const bf16x8*)(rp_ + cA0); \
            bfn[jj][1] = *(const bf16x8*)(rp_ + cA1); } } while (0)

#define MFMAQ(qm, BARR) do { \
        __builtin_amdgcn_s_setprio(1); \
        _Pragma("unroll") \
        for (int i = 0; i < 4; i++) \
            _Pragma("unroll") \
            for (int jj = 0; jj < 2; jj++) { \
                acc[(qm)*4+i][(BQ)*2+jj] = __builtin_amdgcn_mfma_f32_16x16x32_bf16( \
                    af[i][0], BARR[jj][0], acc[(qm)*4+i][(BQ)*2+jj], 0, 0, 0); \
                acc[(qm)*4+i][(BQ)*2+jj] = __builtin_amdgcn_mfma_f32_16x16x32_bf16( \
                    af[i][1], BARR[jj][1], acc[(qm)*4+i][(BQ)*2+jj], 0, 0, 0); \
            } \
        __builtin_amdgcn_s_setprio(0); \
    } while (0)

    // ---- prologue ----
    if (EPI == 0) {
        STGA(0, 0); STGA(1, 0); STGB(0, 0); STGB(1, 0);   // tile0 (8 oldest)
        STGA(0, 1); STGB(0, 1); STGB(1, 1);               // tile1 partial
        asm volatile("s_waitcnt vmcnt(6)" ::: "memory");  // tile0 resident
    } else {
        STGA(0, 0); STGA(1, 0); STGA(0, 1);               // 6 async16 (A)
        BLD(0, 0); BWR(0, 0); BLD(0, 1); BWR(0, 1);       // B tile0
        BLD(1, 0); BWR(1, 0); BLD(1, 1); BWR(1, 1);       // B tile1
        asm volatile("s_waitcnt vmcnt(2) lgkmcnt(0)" ::: "memory");
    }
    BAR();
    {   // prefetch B0 quadrant of tile 0
        const bf16_t* Bb0 = lds + 16384;
        LOADB0N(Bb0);
    }

    for (int j = 0; j < NT; ++j) {
        const bf16_t* Ab = lds + (j & 1) * 32768;
        const bf16_t* Bb = Ab + 16384;
        // ---- q0: M(0,0) = A0 x B0(bfn)
        LOADA(0);
        if (EPI == 1 && j + 2 < NT) BLD(j + 2, 0);
        if (j + 1 < NT) STGA(1, j + 1);
        BAR();
        { enum { BQ = 0 }; MFMAQ(0, bfn); }
        BAR();
        // ---- q1: M(0,1) = A0 x B1   (last B-LDS-read of current buffer)
        LOADB1();
        BAR();
        { enum { BQ = 1 }; MFMAQ(0, bf1); }
        BAR();
        // ---- q2: M(1,0) = A1 x B0(bfn); B region of current buf now writable
        LOADA(1);
        if (EPI == 0 && j + 2 < NT) { STGB(0, j + 2); STGB(1, j + 2); }
        if (EPI == 1 && j + 2 < NT) { BWR(j + 2, 0); BLD(j + 2, 1); }
        BAR();
        { enum { BQ = 0 }; MFMAQ(1, bfn); }
        BAR();
        // ---- q3: M(1,1) = A1 x B1; finish staging tile j+2; certify tile j+1
        if (j + 2 < NT) {
            if (EPI == 1) BWR(j + 2, 1);
            STGA(0, j + 2);
            if (EPI == 0) asm volatile("s_waitcnt vmcnt(6)" ::: "memory");
            else          asm volatile("s_waitcnt vmcnt(2) lgkmcnt(0)" ::: "memory");
        } else if (j + 1 < NT) {
            asm volatile("s_waitcnt vmcnt(0)" ::: "memory");
        }
        BAR();
        if (j + 1 < NT) {
            const bf16_t* Bbn = lds + (((j + 1) & 1) * 32768) + 16384;
            LOADB0N(Bbn);
        }
        { enum { BQ = 1 }; MFMAQ(1, bf1); }
        BAR();
    }

    // ---- epilogue: frag (row,col): row = lkq*4 + reg (+frag base), col = lane&15
    int rbase = lkq * 4;
    if (EPI == 0) {
        #pragma unroll
        for (int mi = 0; mi < 8; mi++) {
            int row = row0 + wm * 128 + mi * 16 + rbase;
            #pragma unroll
            for (int nj = 0; nj < 4; nj++) {
                int col = col0 + wn * 64 + nj * 16 + lm;
                #pragma unroll
                for (int r = 0; r < 4; r++) {
                    float v = acc[mi][nj][r];
                    v = 0.5f * v * (1.0f + erff(v * 0.70710678118f));
                    Hout[((size_t)e * Mcap + row + r) * FFN_ + col] = (bf16_t)v;
                }
            }
        }
    } else if (paired) {
        #pragma unroll
        for (int mi = 0; mi < 8; mi++) {
            #pragma unroll
            for (int r = 0; r < 4; r++) {
                int u   = e * 1024 + row0 + wm * 128 + mi * 16 + rbase + r;
                int tok = inv[2 * u] / TOPK;
                #pragma unroll
                for (int nj = 0; nj < 4; nj++) {
                    int col = col0 + wn * 64 + nj * 16 + lm;
                    Out[(size_t)tok * HIDDEN + col] = 2.0f * acc[mi][nj][r];
                }
            }
        }
    } else {
        #pragma unroll
        for (int mi = 0; mi < 8; mi++) {
            #pragma unroll
            for (int r = 0; r < 4; r++) {
                int gm  = e * 2048 + row0 + wm * 128 + mi * 16 + rbase + r;
                int tok = inv[gm] / TOPK;
                #pragma unroll
                for (int nj = 0; nj < 4; nj++) {
                    int col = col0 + wn * 64 + nj * 16 + lm;
                    atomicAdd(&Out[(size_t)tok * HIDDEN + col], acc[mi][nj][r]);
                }
            }
        }
    }
#undef APTR
#undef STGA
#undef STGB
#undef BLD
#undef BWR
#undef LOADA
#undef LOADB1
#undef LOADB0N
#undef MFMAQ
}

extern "C" void kernel_launch(void* const* d_in, const int* in_sizes, int n_in,
                              void* d_out, int out_size, void* d_ws, size_t ws_size,
                              hipStream_t stream) {
    const float* x    = (const float*)d_in[0];
    const float* w1   = (const float*)d_in[1];
    const float* w2   = (const float*)d_in[2];
    const int*   scat = (const int*)d_in[3];
    float* out = (float*)d_out;

    char* ws = (char*)d_ws;
    size_t off = 0;
    int*    inv   = (int*)(ws + off);   off += 65536;                          // MTOT*4
    int*    flagp = (int*)(ws + off);   off += 256;
    bf16_t* xbt = (bf16_t*)(ws + off);  off += (size_t)NTOK * HIDDEN * 2;      // 32 MB
    bf16_t* w1b = (bf16_t*)(ws + off);  off += (size_t)NEXP * FFN_ * HIDDEN * 2;
    bf16_t* hb  = (bf16_t*)(ws + off);  off += (size_t)MTOT * FFN_ * 2;        // 64 MB

    hipMemsetAsync(flagp, 0, 4, stream);

    k_prep<<<2048, 256, 0, stream>>>(scat, inv, flagp, x, xbt);
    k_zero<<<2048, 256, 0, stream>>>(out, flagp);
    k_wcast<<<2048, 256, 0, stream>>>(w1, w1b);

    k_gemm<0><<<NEXP * 64, 512, 0, stream>>>(xbt, w1b, nullptr, hb, nullptr, inv, flagp);
    k_gemm<1><<<NEXP * 64, 512, 0, stream>>>(hb, nullptr, w2, nullptr, out, inv, flagp);
}